// Round 9
// baseline (981.009 us; speedup 1.0000x reference)
//
#include <hip/hip_runtime.h>
#include <math.h>

// SE block: x[B,C,T] fp32 -> mean over T -> MLP (C->H relu, H->C sigmoid) -> x * w[b,c]
// B=64, C=512, T=4096, H=64. Memory-bound.
// CHUNKED PIPELINE: process 16 batches (128 MiB) at a time:
//   mean(chunk) -> mlp(chunk) -> scale(chunk)
// The chunk fits in the 256 MiB Infinity Cache, so scale's re-read of x is
// ~all L3 hits. NT stores on the output keep x's lines resident.
// HBM floor: 512 MiB read (mean) + ~0 (scale read) + 512 MiB write = 1.02 GB.

#define SE_B 64
#define SE_C 512
#define SE_T 4096
#define SE_H 64
#define SE_ROWS (SE_B * SE_C)   // 32768
#define CHUNK_B 16              // batches per chunk (128 MiB of x)
#define N_CHUNKS (SE_B / CHUNK_B)
#define CHUNK_ROWS (CHUNK_B * SE_C)  // 8192

typedef float fv4 __attribute__((ext_vector_type(4)));

// ---------------- Kernel 1: mean over T per (b,c) row ----------------
// One block per row within the chunk. 256 threads x 4 float4 = 4096 floats.
__global__ __launch_bounds__(256) void se_mean(const float* __restrict__ x,
                                               float* __restrict__ sq) {
    const int row = blockIdx.x;
    const fv4* __restrict__ xr =
        reinterpret_cast<const fv4*>(x + (size_t)row * SE_T);
    const int t = threadIdx.x;
    fv4 a = xr[t];
    fv4 b = xr[t + 256];
    fv4 c = xr[t + 512];
    fv4 d = xr[t + 768];
    float s = ((a.x + a.y) + (a.z + a.w)) + ((b.x + b.y) + (b.z + b.w)) +
              ((c.x + c.y) + (c.z + c.w)) + ((d.x + d.y) + (d.z + d.w));
#pragma unroll
    for (int off = 32; off > 0; off >>= 1) s += __shfl_down(s, off, 64);
    __shared__ float wsum[4];
    if ((t & 63) == 0) wsum[t >> 6] = s;
    __syncthreads();
    if (t == 0)
        sq[row] = ((wsum[0] + wsum[1]) + (wsum[2] + wsum[3])) * (1.0f / SE_T);
}

// ---------------- Kernel 2: excitation MLP per batch ----------------
// One block per batch element in the chunk; negligible FLOPs.
__global__ __launch_bounds__(256) void se_mlp(const float* __restrict__ sq,
                                              const float* __restrict__ W1,
                                              const float* __restrict__ b1,
                                              const float* __restrict__ W2,
                                              const float* __restrict__ b2,
                                              float* __restrict__ wt) {
    const int b = blockIdx.x;  // batch within chunk
    __shared__ float s[SE_C];
    __shared__ float h[SE_H];
    const int t = threadIdx.x;

    for (int c = t; c < SE_C; c += 256) s[c] = sq[b * SE_C + c];
    __syncthreads();

    // hidden layer: 64 outputs, 4 lane-adjacent threads per output
    {
        const int j = t >> 2;  // 0..63
        const int q = t & 3;
        const float* __restrict__ w = W1 + (size_t)j * SE_C;
        float acc = 0.f;
        for (int c = q; c < SE_C; c += 4) acc = fmaf(w[c], s[c], acc);
        acc += __shfl_xor(acc, 1, 64);
        acc += __shfl_xor(acc, 2, 64);
        if (q == 0) h[j] = fmaxf(acc + b1[j], 0.f);
    }
    __syncthreads();

    // output layer: 512 sigmoids, 2 per thread
#pragma unroll
    for (int k = 0; k < 2; ++k) {
        const int c = t + k * 256;
        const float* __restrict__ w = W2 + (size_t)c * SE_H;
        float acc = b2[c];
#pragma unroll
        for (int j = 0; j < SE_H; ++j) acc = fmaf(w[j], h[j], acc);
        wt[b * SE_C + c] = 1.0f / (1.0f + expf(-acc));
    }
}

// ---------------- Kernel 3: channel-wise scale ----------------
// One block per row within the chunk (x just streamed by se_mean -> L3 hot).
// Weight is wave-uniform (scalar load). NT stores: don't evict x's lines.
__global__ __launch_bounds__(256) void se_scale(const float* __restrict__ x,
                                                const float* __restrict__ wt,
                                                float* __restrict__ out) {
    const int row = blockIdx.x;
    const float w = wt[row];
    const fv4* __restrict__ xr =
        reinterpret_cast<const fv4*>(x + (size_t)row * SE_T);
    fv4* __restrict__ orow = reinterpret_cast<fv4*>(out + (size_t)row * SE_T);
    const int t = threadIdx.x;
#pragma unroll
    for (int k = 0; k < 4; ++k) {
        fv4 v = xr[t + k * 256];
        v *= w;
        __builtin_nontemporal_store(v, &orow[t + k * 256]);
    }
}

extern "C" void kernel_launch(void* const* d_in, const int* in_sizes, int n_in,
                              void* d_out, int out_size, void* d_ws,
                              size_t ws_size, hipStream_t stream) {
    const float* x = (const float*)d_in[0];
    const float* W1 = (const float*)d_in[1];
    const float* b1 = (const float*)d_in[2];
    const float* W2 = (const float*)d_in[3];
    const float* b2 = (const float*)d_in[4];
    float* out = (float*)d_out;

    float* sq = (float*)d_ws;      // [B*C] means
    float* wt = sq + SE_ROWS;      // [B*C] sigmoid weights

    for (int ch = 0; ch < N_CHUNKS; ++ch) {
        const size_t roff = (size_t)ch * CHUNK_ROWS;          // row offset
        const size_t xoff = roff * SE_T;                      // element offset
        se_mean<<<CHUNK_ROWS, 256, 0, stream>>>(x + xoff, sq + roff);
        se_mlp<<<CHUNK_B, 256, 0, stream>>>(sq + roff, W1, b1, W2, b2,
                                            wt + roff);
        se_scale<<<CHUNK_ROWS, 256, 0, stream>>>(x + xoff, wt + roff,
                                                 out + xoff);
    }
}

// Round 14
// 933.823 us; speedup vs baseline: 1.0505x; 1.0505x over previous
//
#include <hip/hip_runtime.h>
#include <math.h>

// SE block: x[B,C,T] fp32 -> mean over T -> MLP (C->H relu, H->C sigmoid) -> x * w[b,c]
// B=64, C=512, T=4096, H=64. Memory-bound: 2 reads + 1 write of 512 MiB each.
// MONOLITHIC (chunking regressed: R9 981 vs R4 937.7 — mlp bubbles + dispatch
// drain tails). Scan directions: mean walks rows in REVERSE, scale FORWARD.
//  - mean(rev) ends on low rows => L3 holds x's low half when scale starts;
//    scale(fwd) reads low rows first => same handoff as R4 (symmetric).
//  - bonus: if the harness's d_in restore leaves x's tail L3-resident,
//    mean(rev) reads that tail FIRST and collects those hits too (R4's
//    forward mean started at restore's coldest lines and could not).
// NT stores on out: don't evict x's resident lines.

#define SE_B 64
#define SE_C 512
#define SE_T 4096
#define SE_H 64
#define SE_ROWS (SE_B * SE_C)  // 32768

typedef float fv4 __attribute__((ext_vector_type(4)));

// ---------------- Kernel 1: mean over T per (b,c) row (REVERSE scan) -------
// One block per row. 256 threads x 4 float4 = 4096 floats.
__global__ __launch_bounds__(256) void se_mean(const float* __restrict__ x,
                                               float* __restrict__ sq) {
    const int row = (SE_ROWS - 1) - (int)blockIdx.x;
    const fv4* __restrict__ xr =
        reinterpret_cast<const fv4*>(x + (size_t)row * SE_T);
    const int t = threadIdx.x;
    // 4 independent loads, no loop-carried deps
    fv4 a = xr[t];
    fv4 b = xr[t + 256];
    fv4 c = xr[t + 512];
    fv4 d = xr[t + 768];
    float s = ((a.x + a.y) + (a.z + a.w)) + ((b.x + b.y) + (b.z + b.w)) +
              ((c.x + c.y) + (c.z + c.w)) + ((d.x + d.y) + (d.z + d.w));
#pragma unroll
    for (int off = 32; off > 0; off >>= 1) s += __shfl_down(s, off, 64);
    __shared__ float wsum[4];
    if ((t & 63) == 0) wsum[t >> 6] = s;
    __syncthreads();
    if (t == 0)
        sq[row] = ((wsum[0] + wsum[1]) + (wsum[2] + wsum[3])) * (1.0f / SE_T);
}

// ---------------- Kernel 2: excitation MLP per batch ----------------
// One block per batch element; ~4 MFLOP total across the grid — negligible.
__global__ __launch_bounds__(256) void se_mlp(const float* __restrict__ sq,
                                              const float* __restrict__ W1,
                                              const float* __restrict__ b1,
                                              const float* __restrict__ W2,
                                              const float* __restrict__ b2,
                                              float* __restrict__ wt) {
    const int b = blockIdx.x;  // 0..B-1
    __shared__ float s[SE_C];
    __shared__ float h[SE_H];
    const int t = threadIdx.x;

    for (int c = t; c < SE_C; c += 256) s[c] = sq[b * SE_C + c];
    __syncthreads();

    // hidden layer: 64 outputs, 4 lane-adjacent threads per output
    {
        const int j = t >> 2;  // 0..63
        const int q = t & 3;
        const float* __restrict__ w = W1 + (size_t)j * SE_C;
        float acc = 0.f;
        for (int c = q; c < SE_C; c += 4) acc = fmaf(w[c], s[c], acc);
        acc += __shfl_xor(acc, 1, 64);
        acc += __shfl_xor(acc, 2, 64);
        if (q == 0) h[j] = fmaxf(acc + b1[j], 0.f);
    }
    __syncthreads();

    // output layer: 512 sigmoids, 2 per thread
#pragma unroll
    for (int k = 0; k < 2; ++k) {
        const int c = t + k * 256;
        const float* __restrict__ w = W2 + (size_t)c * SE_H;
        float acc = b2[c];
#pragma unroll
        for (int j = 0; j < SE_H; ++j) acc = fmaf(w[j], h[j], acc);
        wt[b * SE_C + c] = 1.0f / (1.0f + expf(-acc));
    }
}

// ---------------- Kernel 3: channel-wise scale (FORWARD scan) ----------------
// One block per row; weight is wave-uniform (scalar load). Low rows were the
// last thing se_mean touched -> L3 hits first. NT stores keep x resident.
__global__ __launch_bounds__(256) void se_scale(const float* __restrict__ x,
                                                const float* __restrict__ wt,
                                                float* __restrict__ out) {
    const int row = blockIdx.x;
    const float w = wt[row];
    const fv4* __restrict__ xr =
        reinterpret_cast<const fv4*>(x + (size_t)row * SE_T);
    fv4* __restrict__ orow = reinterpret_cast<fv4*>(out + (size_t)row * SE_T);
    const int t = threadIdx.x;
#pragma unroll
    for (int k = 0; k < 4; ++k) {
        fv4 v = xr[t + k * 256];
        v *= w;
        __builtin_nontemporal_store(v, &orow[t + k * 256]);
    }
}

extern "C" void kernel_launch(void* const* d_in, const int* in_sizes, int n_in,
                              void* d_out, int out_size, void* d_ws,
                              size_t ws_size, hipStream_t stream) {
    const float* x = (const float*)d_in[0];
    const float* W1 = (const float*)d_in[1];
    const float* b1 = (const float*)d_in[2];
    const float* W2 = (const float*)d_in[3];
    const float* b2 = (const float*)d_in[4];
    float* out = (float*)d_out;

    float* sq = (float*)d_ws;      // [B*C] means
    float* wt = sq + SE_ROWS;      // [B*C] sigmoid weights

    se_mean<<<SE_ROWS, 256, 0, stream>>>(x, sq);
    se_mlp<<<SE_B, 256, 0, stream>>>(sq, W1, b1, W2, b2, wt);
    se_scale<<<SE_ROWS, 256, 0, stream>>>(x, wt, out);
}